// Round 9
// baseline (139.377 us; speedup 1.0000x reference)
//
#include <hip/hip_runtime.h>
#include <hip/hip_fp16.h>

// fePAM: per-pixel gather attention. Shapes fixed by setup_inputs().
constexpr int B = 2, C = 64, H = 128, W = 256, N = H * W, K = 32;

typedef _Float16 hf2 __attribute__((ext_vector_type(2)));

// DPP helper (VALU-pipe cross-lane)
template <int CTRL>
__device__ __forceinline__ float dppf(float x) {
    int i = __builtin_bit_cast(int, x);
    int r = __builtin_amdgcn_update_dpp(i, i, CTRL, 0xF, 0xF, false);
    return __builtin_bit_cast(float, r);
}
// 0xB1 quad_perm xor1 | 0x4E quad_perm xor2 | 0x141 row_half_mirror (xor4)
// 0x128 row_ror:8 == xor8 within a 16-lane row

__device__ __forceinline__ unsigned sel4(const uint4& v, int g) {
    return g == 0 ? v.x : g == 1 ? v.y : g == 2 ? v.z : v.w;
}
__device__ __forceinline__ unsigned sel4(const ushort4& v, int g) {
    return g == 0 ? v.x : g == 1 ? v.y : g == 2 ? v.z : v.w;
}

// ---------------------------------------------------------------------------
// Prep: z=0/1/2 transpose+fp16 S,R,Q: [B][C][N] -> [B][N][C].
// z=3: pack idx16[n][slot]=px*W+py, slot=(k&7)*4+(k>>3); split across b.
// grid = (N/64, B, 4), block = 256.
// ---------------------------------------------------------------------------
__global__ __launch_bounds__(256) void fepam_prep(
    const float* __restrict__ Q, const float* __restrict__ S,
    const float* __restrict__ R,
    const int* __restrict__ Px, const int* __restrict__ Py,
    __half* __restrict__ Qt, __half* __restrict__ St, __half* __restrict__ Rt,
    unsigned short* __restrict__ Idx) {
    const int n0 = blockIdx.x * 64;
    const int b  = blockIdx.y;
    const int z  = blockIdx.z;

    if (z == 3) {  // idx pack: b=0 handles first 1024 entries, b=1 the rest
#pragma unroll
        for (int t = 0; t < 4; ++t) {
            const int e  = b * 1024 + threadIdx.x + 256 * t;  // 0..2047
            const int nl = e >> 5, k = e & 31;
            const int n  = n0 + nl;
            const int idx = Px[(size_t)n * K + k] * W + Py[(size_t)n * K + k];
            Idx[(size_t)n * K + (k & 7) * 4 + (k >> 3)] = (unsigned short)idx;
        }
        return;
    }

    __shared__ float tile[C][65];
    const float* src = (z == 0 ? S : (z == 1 ? R : Q)) + (size_t)b * C * N;
    __half2* d2 = (__half2*)((z == 0 ? St : (z == 1 ? Rt : Qt)) +
                             (size_t)b * N * C);
    {
        const int j = threadIdx.x & 63, c0 = threadIdx.x >> 6;
        const float* s = src + n0 + j;
#pragma unroll
        for (int r = 0; r < 16; ++r) {
            int c = c0 + r * 4;
            tile[c][j] = s[(size_t)c * N];  // coalesced 256B along n
        }
    }
    __syncthreads();
    {
        const int c2 = threadIdx.x & 31, j0 = threadIdx.x >> 5;
#pragma unroll
        for (int r = 0; r < 8; ++r) {
            int j = j0 + 8 * r;
            d2[(size_t)(n0 + j) * 32 + c2] =
                __floats2half2_rn(tile[2 * c2][j], tile[2 * c2 + 1][j]);
        }
    }
}

// ---------------------------------------------------------------------------
// Scores: touches ONLY St (4.19 MB/batch -> ~L2-resident per XCD).
// grid = (N/32 * B), block = 256 (4 waves; 1 wave = 8 pixels). No LDS.
// Dual-pixel pipeline: keys for the NEXT pixel-pair (8 loads) in flight while
// computing the current pair -> 2x memory-level parallelism per wave at the
// same occupancy tier (VGPR target ~110-125, capped 128 by launch_bounds).
// Writes packed (idx<<16 | fp16 attn) to AI[b][n][k_loc*4+g].
// ---------------------------------------------------------------------------
__global__ __launch_bounds__(256, 4) void fepam_scores(
    const __half* __restrict__ Qt, const unsigned short* __restrict__ Idx,
    const __half* __restrict__ St, unsigned* __restrict__ AI) {
    const int tid  = threadIdx.x;
    const int lane = tid & 63;
    const int wave = tid >> 6;        // 0..3
    const int bx   = blockIdx.x;
    const int b    = bx & 1;          // XCD batch-parity swizzle
    const int n0   = (bx >> 1) * 32 + wave * 8;

    const int c_oct = lane & 7;
    const int k_loc = lane >> 3;

    const __half* Qtb = Qt + (size_t)b * N * C;
    const __half* Stb = St + (size_t)b * N * C;
    unsigned* AIb = AI + (size_t)b * N * K;

    auto ldi = [&](int p) {
        return *(const ushort4*)(Idx + (size_t)(n0 + p) * K + k_loc * 4);
    };
    auto ldq = [&](int p) {
        return *(const float4*)(Qtb + (size_t)(n0 + p) * C + c_oct * 8);
    };
    auto ldk = [&](const ushort4& iv, int g) {
        return *(const float4*)(Stb + ((size_t)sel4(iv, g) << 6) + c_oct * 8);
    };

    ushort4 ivA[2] = {ldi(0), ldi(1)};
    ushort4 ivB[2] = {ldi(2), ldi(3)};
    float4  qA[2]  = {ldq(0), ldq(1)};
    float4  qB[2]  = {ldq(2), ldq(3)};
    float4  kA[2][4];
#pragma unroll
    for (int pp = 0; pp < 2; ++pp)
#pragma unroll
        for (int g = 0; g < 4; ++g) kA[pp][g] = ldk(ivA[pp], g);

#pragma unroll
    for (int pair = 0; pair < 4; ++pair) {
        const int pbase = pair * 2;

        // prefetch next pair's keys (8 loads) + pair-after-next iv/q
        float4 kB[2][4];
        if (pair < 3) {
#pragma unroll
            for (int pp = 0; pp < 2; ++pp)
#pragma unroll
                for (int g = 0; g < 4; ++g) kB[pp][g] = ldk(ivB[pp], g);
        }
        ushort4 ivC[2];
        float4  qC[2];
        if (pair < 2) {
            ivC[0] = ldi(pbase + 4); ivC[1] = ldi(pbase + 5);
            qC[0]  = ldq(pbase + 4); qC[1]  = ldq(pbase + 5);
        }

        // ---- compute the two current pixels
#pragma unroll
        for (int pp = 0; pp < 2; ++pp) {
            float s[4];
#pragma unroll
            for (int g = 0; g < 4; ++g) {
                const hf2* k2 = (const hf2*)&kA[pp][g];
                const hf2* q2 = (const hf2*)&qA[pp];
                float acc = 0.f;
#pragma unroll
                for (int u = 0; u < 4; ++u)
                    acc = __builtin_amdgcn_fdot2(k2[u], q2[u], acc, false);
                s[g] = acc;
            }
#pragma unroll
            for (int g = 0; g < 4; ++g) {  // reduce over c_oct: pure DPP
                s[g] += dppf<0xB1>(s[g]);
                s[g] += dppf<0x4E>(s[g]);
                s[g] += dppf<0x141>(s[g]);
            }
            float m = fmaxf(fmaxf(s[0], s[1]), fmaxf(s[2], s[3]));
            m = fmaxf(m, dppf<0x128>(m));
            m = fmaxf(m, __shfl_xor(m, 16));
            m = fmaxf(m, __shfl_xor(m, 32));
            float e0 = __expf(s[0] - m), e1 = __expf(s[1] - m);
            float e2 = __expf(s[2] - m), e3 = __expf(s[3] - m);
            float l = (e0 + e1) + (e2 + e3);
            l += dppf<0x128>(l);
            l += __shfl_xor(l, 16);
            l += __shfl_xor(l, 32);
            const float inv = 1.0f / l;

            if (c_oct == 0) {  // 8 lanes x 16B = contiguous 128B per pixel
                uint4 wv;
                wv.x = ((unsigned)ivA[pp].x << 16) |
                       __half_as_ushort(__float2half_rn(e0 * inv));
                wv.y = ((unsigned)ivA[pp].y << 16) |
                       __half_as_ushort(__float2half_rn(e1 * inv));
                wv.z = ((unsigned)ivA[pp].z << 16) |
                       __half_as_ushort(__float2half_rn(e2 * inv));
                wv.w = ((unsigned)ivA[pp].w << 16) |
                       __half_as_ushort(__float2half_rn(e3 * inv));
                *(uint4*)(AIb + (size_t)(n0 + pbase + pp) * K + k_loc * 4) = wv;
            }
        }

        // ---- shift pipeline
#pragma unroll
        for (int pp = 0; pp < 2; ++pp) {
#pragma unroll
            for (int g = 0; g < 4; ++g) kA[pp][g] = kB[pp][g];
            ivA[pp] = ivB[pp]; qA[pp] = qB[pp];
            ivB[pp] = ivC[pp]; qB[pp] = qC[pp];
        }
    }
}

// ---------------------------------------------------------------------------
// Values: touches ONLY Rt (4.19 MB/batch -> ~L2-resident per XCD).
// grid = (N/32 * B), block = 256 (4 waves; 1 wave = 8 pixels). LDS 8.4 KB.
// Dual-pixel pipeline like fepam_scores; reads packed (idx|attn) words.
// ---------------------------------------------------------------------------
__global__ __launch_bounds__(256, 4) void fepam_values(
    const unsigned* __restrict__ AI, const __half* __restrict__ Rt,
    float* __restrict__ Out) {
    __shared__ __align__(16) float ot[32][66];  // 8.4 KB

    const int tid  = threadIdx.x;
    const int lane = tid & 63;
    const int wave = tid >> 6;        // 0..3
    const int bx   = blockIdx.x;
    const int b    = bx & 1;
    const int n0t  = (bx >> 1) * 32;
    const int n0   = n0t + wave * 8;

    const int c_oct = lane & 7;
    const int k_loc = lane >> 3;
    const bool hi8  = (lane & 8)  != 0;
    const bool hi16 = (lane & 16) != 0;
    const bool hi32 = (lane & 32) != 0;

    const __half* Rtb = Rt + (size_t)b * N * C;
    const unsigned* AIb = AI + (size_t)b * N * K;

    auto ldw = [&](int p) {
        return *(const uint4*)(AIb + (size_t)(n0 + p) * K + k_loc * 4);
    };
    auto ldv = [&](const uint4& wv, int g) {
        return *(const float4*)(Rtb + ((size_t)(sel4(wv, g) >> 16) << 6) +
                                c_oct * 8);
    };

    uint4 wA[2] = {ldw(0), ldw(1)};
    uint4 wB[2] = {ldw(2), ldw(3)};
    float4 vA[2][4];
#pragma unroll
    for (int pp = 0; pp < 2; ++pp)
#pragma unroll
        for (int g = 0; g < 4; ++g) vA[pp][g] = ldv(wA[pp], g);

#pragma unroll
    for (int pair = 0; pair < 4; ++pair) {
        const int pbase = pair * 2;

        float4 vB[2][4];
        if (pair < 3) {
#pragma unroll
            for (int pp = 0; pp < 2; ++pp)
#pragma unroll
                for (int g = 0; g < 4; ++g) vB[pp][g] = ldv(wB[pp], g);
        }
        uint4 wC[2];
        if (pair < 2) { wC[0] = ldw(pbase + 4); wC[1] = ldw(pbase + 5); }

        // ---- compute the two current pixels
#pragma unroll
        for (int pp = 0; pp < 2; ++pp) {
            const uint4 wc = wA[pp];
            const float a[4] = {
                __half2float(__ushort_as_half((unsigned short)(wc.x & 0xffffu))),
                __half2float(__ushort_as_half((unsigned short)(wc.y & 0xffffu))),
                __half2float(__ushort_as_half((unsigned short)(wc.z & 0xffffu))),
                __half2float(__ushort_as_half((unsigned short)(wc.w & 0xffffu)))};
            float acc[8] = {0, 0, 0, 0, 0, 0, 0, 0};
#pragma unroll
            for (int g = 0; g < 4; ++g) {
                const __half2* v2 = (const __half2*)&vA[pp][g];
#pragma unroll
                for (int u = 0; u < 4; ++u) {
                    const float2 vf = __half22float2(v2[u]);
                    acc[2 * u]     = fmaf(a[g], vf.x, acc[2 * u]);
                    acc[2 * u + 1] = fmaf(a[g], vf.y, acc[2 * u + 1]);
                }
            }

            // reduce acc[8] over k_loc (xor 8,16,32) with payload halving
            float r4[4];
#pragma unroll
            for (int i = 0; i < 4; ++i) {
                const float send = hi8 ? acc[i] : acc[4 + i];
                const float recv = dppf<0x128>(send);
                r4[i] = (hi8 ? acc[4 + i] : acc[i]) + recv;
            }
            float r2[2];
#pragma unroll
            for (int i = 0; i < 2; ++i) {
                const float send = hi16 ? r4[i] : r4[2 + i];
                const float recv = __shfl_xor(send, 16);
                r2[i] = (hi16 ? r4[2 + i] : r4[i]) + recv;
            }
            {
                const float send = hi32 ? r2[0] : r2[1];
                const float recv = __shfl_xor(send, 32);
                const float r1   = (hi32 ? r2[1] : r2[0]) + recv;
                const int c = c_oct * 8 + (hi8 ? 4 : 0) + (hi16 ? 2 : 0) +
                              (hi32 ? 1 : 0);
                ot[wave * 8 + pbase + pp][c] = r1;
            }
        }

        // ---- shift pipeline
#pragma unroll
        for (int pp = 0; pp < 2; ++pp) {
#pragma unroll
            for (int g = 0; g < 4; ++g) vA[pp][g] = vB[pp][g];
            wA[pp] = wB[pp];
            wB[pp] = wC[pp];
        }
    }
    __syncthreads();

    // store: ot[j][c] -> Out[b][c][n0t+j] (128B segments per instr)
    {
        const int j = tid & 31, c0 = tid >> 5;
        float* od = Out + (size_t)b * C * N + n0t + j;
#pragma unroll
        for (int r = 0; r < 8; ++r) {
            int c = c0 + r * 8;
            od[(size_t)c * N] = ot[j][c];
        }
    }
}

// ---------------------------------------------------------------------------
extern "C" void kernel_launch(void* const* d_in, const int* in_sizes, int n_in,
                              void* d_out, int out_size, void* d_ws, size_t ws_size,
                              hipStream_t stream) {
    const float* Q  = (const float*)d_in[0];
    const float* S  = (const float*)d_in[1];
    const float* R  = (const float*)d_in[2];
    const int*   Px = (const int*)d_in[3];
    const int*   Py = (const int*)d_in[4];
    float* Out = (float*)d_out;

    // ws: St, Rt, Qt (8.39 MB each) + Idx (2.1 MB) + AI packed (8.39 MB)
    __half* St = (__half*)d_ws;
    __half* Rt = St + (size_t)B * N * C;
    __half* Qt = Rt + (size_t)B * N * C;
    unsigned short* Idx = (unsigned short*)(Qt + (size_t)B * N * C);
    unsigned* AI = (unsigned*)(Idx + (size_t)N * K);

    dim3 pgrid(N / 64, B, 4);
    fepam_prep<<<pgrid, 256, 0, stream>>>(Q, S, R, Px, Py, Qt, St, Rt, Idx);

    dim3 ggrid(N / 32 * B);
    fepam_scores<<<ggrid, 256, 0, stream>>>(Qt, Idx, St, AI);
    fepam_values<<<ggrid, 256, 0, stream>>>(AI, Rt, Out);
}